// Round 10
// baseline (175.229 us; speedup 1.0000x reference)
//
#include <hip/hip_runtime.h>

typedef unsigned short u16;
typedef __attribute__((ext_vector_type(8))) short bf16x8;
typedef __attribute__((ext_vector_type(4))) float f32x4;
typedef __attribute__((ext_vector_type(4))) unsigned short u16x4;
typedef __attribute__((ext_vector_type(8))) unsigned short u16x8;

#define AS1 __attribute__((address_space(1)))
#define AS3 __attribute__((address_space(3)))

__device__ __forceinline__ u16 f2b(float f) {
    unsigned u = __float_as_uint(f);
    unsigned r = 0x7fffu + ((u >> 16) & 1u);
    return (u16)((u + r) >> 16);
}

// pack hi16(p1):hi16(p0) in one v_perm_b32 (truncating bf16 convert x2)
__device__ __forceinline__ unsigned packtrunc(float p0, float p1) {
#if __has_builtin(__builtin_amdgcn_perm)
    return __builtin_amdgcn_perm(__float_as_uint(p1), __float_as_uint(p0), 0x07060302u);
#else
    return (__float_as_uint(p0) >> 16) | (__float_as_uint(p1) & 0xffff0000u);
#endif
}

#if __has_builtin(__builtin_amdgcn_exp2f)
#define EXP2(x) __builtin_amdgcn_exp2f(x)
#else
#define EXP2(x) exp2f(x)
#endif

// ---------------------------------------------------------------------------
// Sync machinery (capture-safe). Device globals survive ws re-poison;
// all counters grow monotonically across launches/graph replays.
//   g_cnt/g_gen[1]: the remaining full grid barrier (before phase C).
//   g_acnt[8]: per-batch gemm-producer counts (48 blocks per b per launch).
//   g_mcnt   : MqkT producer count (48 blocks per launch).
// Launch index G = g_gen[1] read at kernel ENTRY — launch-consistent since
// gbar(1) cannot increment until every block of this launch has started.
// ---------------------------------------------------------------------------
__device__ unsigned g_cnt[2];
__device__ unsigned g_gen[2];
__device__ unsigned g_acnt[8];
__device__ unsigned g_mcnt;

__device__ __forceinline__ void gbar(int i, unsigned nblk) {
    __syncthreads();
    if (threadIdx.x == 0) {
        __threadfence();
        const unsigned my = __hip_atomic_load(&g_gen[i], __ATOMIC_RELAXED,
                                              __HIP_MEMORY_SCOPE_AGENT);
        const unsigned v = __hip_atomic_fetch_add(&g_cnt[i], 1u, __ATOMIC_ACQ_REL,
                                                  __HIP_MEMORY_SCOPE_AGENT);
        if (v == nblk - 1u) {
            __hip_atomic_store(&g_cnt[i], 0u, __ATOMIC_RELAXED,
                               __HIP_MEMORY_SCOPE_AGENT);
            __threadfence();
            __hip_atomic_fetch_add(&g_gen[i], 1u, __ATOMIC_ACQ_REL,
                                   __HIP_MEMORY_SCOPE_AGENT);
        } else {
            unsigned spins = 0;
            while (__hip_atomic_load(&g_gen[i], __ATOMIC_ACQUIRE,
                                     __HIP_MEMORY_SCOPE_AGENT) == my) {
                __builtin_amdgcn_s_sleep(2);
                if (++spins > (1u << 22)) break;   // failsafe: never hang
            }
        }
        __threadfence();
    }
    __syncthreads();
}

// ===========================================================================
// Phase A (R8 layout): bid<384 gemm_t 64x64 (inline-G, BK=64, chunk-XOR
// swizzle); 384..431 MqkT; 432..719 Dcat; 720..767 idle.
// Producer counters: gemm block bumps g_acnt[b]; MqkT block bumps g_mcnt.
// ===========================================================================
__device__ __forceinline__ void phaseA(
    const int bid, const int t, char* smem,
    const float* __restrict__ X,
    const float* __restrict__ Wq0, const float* __restrict__ Wq1, const float* __restrict__ Wq2,
    const float* __restrict__ Wk0, const float* __restrict__ Wk1, const float* __restrict__ Wk2,
    const float* __restrict__ Wv0, const float* __restrict__ Wv1, const float* __restrict__ Wv2,
    const float* __restrict__ PW,
    u16* __restrict__ T, u16* __restrict__ tvt,
    u16* __restrict__ MqkT, u16* __restrict__ Dcat)
{
    const f32x4 zero4 = {0.f, 0.f, 0.f, 0.f};
    if (bid < 384) {
        // ---- gemm_t, BK=64: 12 iters. LDS end = 36,096 B.
        u16*   As  = (u16*)smem;                 //  8192 B
        u16*   Bs  = (u16*)(smem + 8192);        //  8192 B
        float* W1t = (float*)(smem + 16384);     //  3072 B  [h*64+r]
        float* W2t = (float*)(smem + 19456);     // 16640 B  [r*65+d]

        const int lane = t & 63, wv = t >> 6;
        const int l15 = lane & 15, quad = lane >> 4;

        const int lin = bid;                     // 0..383
        const int xcd = lin & 7, j = lin >> 3;   // j 0..47
        const int col = j % 3, rowhi = j / 3;    // rowhi 0..15
        const int rowBase = (rowhi * 8 + xcd) * 64;
        const int colBase = col * 64;

        const float* W1g = (col == 0) ? Wq1 : (col == 1) ? Wk1 : Wv1;
        const float* W2g = (col == 0) ? Wq2 : (col == 1) ? Wk2 : Wv2;
        for (int i = t; i < 768; i += 256) W1t[i] = W1g[i];
        for (int i = t; i < 4096; i += 256) {
            const int d = i >> 6, r = i & 63;
            W2t[r * 65 + d] = W2g[i];            // transpose: [r][d]
        }

        const int srow = t >> 2;            // 0..63
        const int sc4  = t & 3;             // chunk pair base = sc4*2
        const int scol = sc4 * 16;          // 0/16/32/48 (u16 cols)
        const int swa = ((sc4 * 2)     ^ (srow & 7)) * 8;
        const int swb = ((sc4 * 2 + 1) ^ (srow & 7)) * 8;
        const float* aS = X + (size_t)(rowBase + srow) * 768 + scol;

        float4 a0 = *(const float4*)(aS);
        float4 a1 = *(const float4*)(aS + 4);
        float4 a2 = *(const float4*)(aS + 8);
        float4 a3 = *(const float4*)(aS + 12);

        f32x4 acc[4];
#pragma unroll
        for (int tn = 0; tn < 4; ++tn) acc[tn] = zero4;

        for (int kk = 0; kk < 768; kk += 64) {
            __syncthreads();
            u16x8 ap0, ap1;
            ap0[0] = f2b(a0.x); ap0[1] = f2b(a0.y); ap0[2] = f2b(a0.z); ap0[3] = f2b(a0.w);
            ap0[4] = f2b(a1.x); ap0[5] = f2b(a1.y); ap0[6] = f2b(a1.z); ap0[7] = f2b(a1.w);
            ap1[0] = f2b(a2.x); ap1[1] = f2b(a2.y); ap1[2] = f2b(a2.z); ap1[3] = f2b(a2.w);
            ap1[4] = f2b(a3.x); ap1[5] = f2b(a3.y); ap1[6] = f2b(a3.z); ap1[7] = f2b(a3.w);
            *(u16x8*)&As[srow * 64 + swa] = ap0;
            *(u16x8*)&As[srow * 64 + swb] = ap1;
            // B-tile: G[colBase+srow][kk+scol .. +15] = W1[h,r]*W2[d,r]
            {
                const int c0 = kk + scol;
                const int hh = c0 >> 6, dd = c0 & 63;   // 16 consec d, same h
                const float w1v = W1t[hh * 64 + srow];
                u16x8 bp0, bp1;
#pragma unroll
                for (int jj = 0; jj < 8; ++jj)
                    bp0[jj] = f2b(w1v * W2t[srow * 65 + dd + jj]);
#pragma unroll
                for (int jj = 0; jj < 8; ++jj)
                    bp1[jj] = f2b(w1v * W2t[srow * 65 + dd + 8 + jj]);
                *(u16x8*)&Bs[srow * 64 + swa] = bp0;
                *(u16x8*)&Bs[srow * 64 + swb] = bp1;
            }
            __syncthreads();

            if (kk < 704) {
                a0 = *(const float4*)(aS + kk + 64);
                a1 = *(const float4*)(aS + kk + 68);
                a2 = *(const float4*)(aS + kk + 72);
                a3 = *(const float4*)(aS + kk + 76);
            }

            const int arow = wv * 16 + l15;
#pragma unroll
            for (int ks = 0; ks < 2; ++ks) {
                const bf16x8 af = *(const bf16x8*)
                    &As[arow * 64 + ((ks * 4 + quad) ^ (arow & 7)) * 8];
#pragma unroll
                for (int tn = 0; tn < 4; ++tn) {
                    const int brow = tn * 16 + l15;
                    const bf16x8 bf = *(const bf16x8*)
                        &Bs[brow * 64 + ((ks * 4 + quad) ^ (brow & 7)) * 8];
                    acc[tn] = __builtin_amdgcn_mfma_f32_16x16x32_bf16(af, bf, acc[tn], 0, 0, 0);
                }
            }
        }

        if (colBase < 128) {
#pragma unroll
            for (int tn = 0; tn < 4; ++tn) {
                const int c = colBase + tn * 16 + l15;
#pragma unroll
                for (int r = 0; r < 4; ++r) {
                    const int grow = rowBase + wv * 16 + quad * 4 + r;
                    T[(size_t)grow * 128 + c] = f2b(acc[tn][r]);
                }
            }
        } else {
#pragma unroll
            for (int tn = 0; tn < 4; ++tn) {
                const int rr = tn * 16 + l15;                    // r index 0..63
                const int grow = rowBase + wv * 16 + quad * 4;   // token base
                u16x4 pk;
                pk.x = f2b(acc[tn][0]); pk.y = f2b(acc[tn][1]);
                pk.z = f2b(acc[tn][2]); pk.w = f2b(acc[tn][3]);
                *(u16x4*)(tvt + (size_t)rr * 8192 + grow) = pk;
            }
        }
        // producer signal: this b's T/tvt contribution is done
        __syncthreads();
        if (t == 0) {
            __threadfence();
            __hip_atomic_fetch_add(&g_acnt[rowBase >> 10], 1u, __ATOMIC_RELEASE,
                                   __HIP_MEMORY_SCOPE_AGENT);
        }
    } else if (bid < 432) {
        // ---- MqkT section (48 blocks) ----
        float* wq = (float*)smem;                // 16640 B
        float* wk = (float*)(smem + 16640);      // 16640 B
        const int hq = bid - 384;                // 0..47
        const int h = hq >> 2, quarter = hq & 3;
        const float qs = 0.125f * 1.4426950408889634f;
        for (int i = t; i < 4096; i += 256) {
            const int dd = i >> 6, r = i & 63;
            wq[dd * 65 + r] = Wq0[(h * 64 + dd) * 64 + r] * qs;
            wk[dd * 65 + r] = Wk0[(h * 64 + dd) * 64 + r];
        }
        __syncthreads();
        const int j0 = quarter * 1024 + t * 4;
        const int r2 = j0 >> 6, r1b = j0 & 63;   // output row = r2, packed cols = r1
        u16x4 pk;
#pragma unroll
        for (int jj = 0; jj < 4; ++jj) {
            float acc = 0.f;
#pragma unroll
            for (int dd = 0; dd < 64; ++dd)
                acc += wk[dd * 65 + r2] * wq[dd * 65 + r1b + jj];
            ((u16*)&pk)[jj] = f2b(acc);
        }
        *(u16x4*)(MqkT + (size_t)(h * 64 + r2) * 64 + r1b) = pk;
        __syncthreads();
        if (t == 0) {
            __threadfence();
            __hip_atomic_fetch_add(&g_mcnt, 1u, __ATOMIC_RELEASE,
                                   __HIP_MEMORY_SCOPE_AGENT);
        }
    } else if (bid < 720) {
        // ---- Dcat section (288 blocks); consumed only after gbar(1) ----
        float* w0s = (float*)smem;               // 16640 B  [d][r]
        float* pws = (float*)(smem + 16640);     //  8320 B  [mi][d]
        const int hb = bid - 432;                // 0..287
        const int h = hb / 24, mBase = (hb - h * 24) * 32;
        for (int i = t; i < 4096; i += 256) {
            const int d = i >> 6, r = i & 63;
            w0s[d * 65 + r] = Wv0[(h * 64 + d) * 64 + r];
        }
        for (int i = t; i < 2048; i += 256) {
            const int mi = i >> 6, d = i & 63;
            pws[mi * 65 + d] = PW[(size_t)(mBase + mi) * 768 + h * 64 + d];
        }
        __syncthreads();
        const int r = t & 63, mi0 = t >> 6;
        float w0c[64];
#pragma unroll
        for (int d = 0; d < 64; ++d) w0c[d] = w0s[d * 65 + r];
        for (int mi = mi0; mi < 32; mi += 4) {
            float acc = 0.f;
#pragma unroll
            for (int d = 0; d < 64; ++d) acc += pws[mi * 65 + d] * w0c[d];
            Dcat[(size_t)(mBase + mi) * 768 + h * 64 + r] = f2b(acc);
        }
    }
}

// ===========================================================================
// Phase B: flash attention v10 body (unchanged). bid in [0, 768).
// ===========================================================================
__device__ __forceinline__ void phaseB(
    const int bid, const int t, char* smem,
    const u16* __restrict__ T, const u16* __restrict__ MqkT,
    const u16* __restrict__ tvt, u16* __restrict__ Zcat)
{
    const int bh = bid % 96;
    const int qt = bid / 96;            // 0..7 (128 q rows each)
    const int b = bh / 12, h = bh - b * 12;
    const u16* qp = T + ((size_t)b * 1024 + qt * 128) * 128;   // t_q rows
    const u16* kp = T + (size_t)b * 1024 * 128 + 64;           // t_k rows
    const u16* vp = tvt + b * 1024;     // tvt[r][8192]

    u16* const B0raw = (u16*)smem;             // [0, 18432) B
    u16* const B1raw = (u16*)(smem + 18432);   // [18432, 36864) B

    const int lane = t & 63, wv = t >> 6;
    const int l15 = lane & 15, quad = lane >> 4;
    const f32x4 zero4 = {0.f, 0.f, 0.f, 0.f};

    // t_q A-fragments (rows = q, cols = r1)
    bf16x8 qf[2][2];
#pragma unroll
    for (int qg = 0; qg < 2; ++qg) {
        const u16* qrow = qp + (size_t)(wv * 32 + qg * 16 + l15) * 128;
        qf[qg][0] = *(const bf16x8*)(qrow + quad * 8);
        qf[qg][1] = *(const bf16x8*)(qrow + 32 + quad * 8);
    }

    const int srow = t >> 2;            // key-row / r-row 0..63
    const int scol = (t & 3) * 16;
    const int p5 = srow & 31;
    const int lrow = (srow & 32) | ((p5 & 4) << 2) | ((p5 & 16) >> 1)
                   | ((p5 & 8) >> 1) | (p5 & 3);   // permuted K row

    bf16x8 vone = {};
    if (l15 == 0) {
#pragma unroll
        for (int j = 0; j < 8; ++j) vone[j] = (short)0x3F80;
    }

    // prefetch tile 0 (t_k + v) — overlaps the Wq prologue
    int4 kr0 = *(const int4*)(kp + (size_t)srow * 128 + scol);
    int4 kr1 = *(const int4*)(kp + (size_t)srow * 128 + scol + 8);
    int4 vr0 = *(const int4*)(vp + (size_t)srow * 8192 + scol);
    int4 vr1 = *(const int4*)(vp + (size_t)srow * 8192 + scol + 8);

    // ---- Wq = t_q x Mqk_h prologue ----
    {
        f32x4 Wt[2][4];
#pragma unroll
        for (int qg = 0; qg < 2; ++qg)
#pragma unroll
            for (int tn = 0; tn < 4; ++tn) Wt[qg][tn] = zero4;
#pragma unroll
        for (int ks = 0; ks < 2; ++ks) {
#pragma unroll
            for (int tn = 0; tn < 4; ++tn) {
                const bf16x8 mb = *(const bf16x8*)(
                    MqkT + (size_t)(h * 64 + tn * 16 + l15) * 64 + ks * 32 + quad * 8);
                Wt[0][tn] = __builtin_amdgcn_mfma_f32_16x16x32_bf16(qf[0][ks], mb, Wt[0][tn], 0, 0, 0);
                Wt[1][tn] = __builtin_amdgcn_mfma_f32_16x16x32_bf16(qf[1][ks], mb, Wt[1][tn], 0, 0, 0);
            }
        }
        // C-layout -> LDS Ws (rows = q_local, cols = r2), Ws = B1raw overlay
#pragma unroll
        for (int qg = 0; qg < 2; ++qg)
#pragma unroll
            for (int tn = 0; tn < 4; ++tn)
#pragma unroll
                for (int r = 0; r < 4; ++r)
                    B1raw[(wv * 32 + qg * 16 + quad * 4 + r) * 72 + tn * 16 + l15] =
                        f2b(Wt[qg][tn][r]);
    }
    __syncthreads();
    // B-fragments of Wq: B[n=q][k=r2]
    bf16x8 wf[2][2];
#pragma unroll
    for (int qg = 0; qg < 2; ++qg) {
        wf[qg][0] = *(const bf16x8*)&B1raw[(wv * 32 + qg * 16 + l15) * 72 + quad * 8];
        wf[qg][1] = *(const bf16x8*)&B1raw[(wv * 32 + qg * 16 + l15) * 72 + 32 + quad * 8];
    }

    // stage tile 0 -> buf0 while everyone still holds wf in regs
    *(int4*)&B0raw[lrow * 72 + scol]                 = kr0;
    *(int4*)&B0raw[lrow * 72 + scol + 8]             = kr1;
    *(int4*)&B0raw[64 * 72 + srow * 72 + scol]       = vr0;
    *(int4*)&B0raw[64 * 72 + srow * 72 + scol + 8]   = vr1;
    // prefetch tile 1 into regs
    kr0 = *(const int4*)(kp + (size_t)(64 + srow) * 128 + scol);
    kr1 = *(const int4*)(kp + (size_t)(64 + srow) * 128 + scol + 8);
    vr0 = *(const int4*)(vp + (size_t)srow * 8192 + 64 + scol);
    vr1 = *(const int4*)(vp + (size_t)srow * 8192 + 64 + scol + 8);
    __syncthreads();   // buf0 visible; all waves past wf-read

    f32x4 o_acc[2][4];
    f32x4 Lacc[2] = {zero4, zero4};
#pragma unroll
    for (int qg = 0; qg < 2; ++qg)
#pragma unroll
        for (int tn = 0; tn < 4; ++tn) o_acc[qg][tn] = zero4;

#define STAGE(NB)                                                               \
    {                                                                           \
        *(int4*)&NB[lrow * 72 + scol]               = kr0;                      \
        *(int4*)&NB[lrow * 72 + scol + 8]           = kr1;                      \
        *(int4*)&NB[64 * 72 + srow * 72 + scol]     = vr0;                      \
        *(int4*)&NB[64 * 72 + srow * 72 + scol + 8] = vr1;                      \
    }
#define PREFETCH(KT)                                                            \
    {                                                                           \
        kr0 = *(const int4*)(kp + (size_t)((KT) * 64 + srow) * 128 + scol);     \
        kr1 = *(const int4*)(kp + (size_t)((KT) * 64 + srow) * 128 + scol + 8); \
        vr0 = *(const int4*)(vp + (size_t)srow * 8192 + (KT) * 64 + scol);      \
        vr1 = *(const int4*)(vp + (size_t)srow * 8192 + (KT) * 64 + scol + 8);  \
    }
#define FLASH_TILE(KB)                                                          \
    {                                                                           \
        f32x4 Sacc[2][4];                                                       \
        _Pragma("unroll")                                                       \
        for (int qg = 0; qg < 2; ++qg)                                          \
            _Pragma("unroll")                                                   \
            for (int tk = 0; tk < 4; ++tk) Sacc[qg][tk] = zero4;                \
        _Pragma("unroll")                                                       \
        for (int ks = 0; ks < 2; ++ks) {                                        \
            _Pragma("unroll")                                                   \
            for (int tk = 0; tk < 4; ++tk) {                                    \
                const bf16x8 kf = *(const bf16x8*)&KB[(tk * 16 + l15) * 72 + ks * 32 + quad * 8]; \
                Sacc[0][tk] = __builtin_amdgcn_mfma_f32_16x16x32_bf16(kf, wf[0][ks], Sacc[0][tk], 0, 0, 0); \
                Sacc[1][tk] = __builtin_amdgcn_mfma_f32_16x16x32_bf16(kf, wf[1][ks], Sacc[1][tk], 0, 0, 0); \
            }                                                                   \
        }                                                                       \
        union { bf16x8 v; unsigned u[4]; } pf[2][2];                            \
        _Pragma("unroll")                                                       \
        for (int qg = 0; qg < 2; ++qg)                                          \
            _Pragma("unroll")                                                   \
            for (int tk = 0; tk < 4; ++tk) {                                    \
                const float p0 = EXP2(Sacc[qg][tk][0]);                         \
                const float p1 = EXP2(Sacc[qg][tk][1]);                         \
                const float p2 = EXP2(Sacc[qg][tk][2]);                         \
                const float p3 = EXP2(Sacc[qg][tk][3]);                         \
                const int g = tk >> 1, hf = (tk & 1) * 2;                       \
                pf[qg][g].u[hf + 0] = packtrunc(p0, p1);                        \
                pf[qg][g].u[hf + 1] = packtrunc(p2, p3);                        \
            }                                                                   \
        _Pragma("unroll")                                                       \
        for (int g = 0; g < 2; ++g) {                                           \
            _Pragma("unroll")                                                   \
            for (int tn = 0; tn < 4; ++tn) {                                    \
                const bf16x8 vf = *(const bf16x8*)&KB[64 * 72 + (tn * 16 + l15) * 72 + g * 32 + quad * 8]; \
                o_acc[0][tn] = __builtin_amdgcn_mfma_f32_16x16x32_bf16(pf[0][g].v, vf, o_acc[0][tn], 0, 0, 0); \
                o_acc[1][tn] = __builtin_amdgcn_mfma_f32_16x16x32_bf16(pf[1][g].v, vf, o_acc[1][tn], 0, 0, 0); \
            }                                                                   \
            Lacc[0] = __builtin_amdgcn_mfma_f32_16x16x32_bf16(pf[0][g].v, vone, Lacc[0], 0, 0, 0); \
            Lacc[1] = __builtin_amdgcn_mfma_f32_16x16x32_bf16(pf[1][g].v, vone, Lacc[1], 0, 0, 0); \
        }                                                                       \
    }

    for (int t8 = 0; t8 < 8; ++t8) {
        const int kt0 = 2 * t8;
        STAGE(B1raw);
        if (t8 < 7) PREFETCH(kt0 + 2);
        FLASH_TILE(B0raw);
        __syncthreads();
        if (t8 < 7) {
            STAGE(B0raw);
            PREFETCH(kt0 + 3);
        }
        FLASH_TILE(B1raw);
        if (t8 < 7) __syncthreads();
    }

#undef STAGE
#undef PREFETCH
#undef FLASH_TILE

    // epilogue: Z[token][h*64 + r'], r' = tn*16+l15
#pragma unroll
    for (int qg = 0; qg < 2; ++qg) {
#pragma unroll
        for (int r = 0; r < 4; ++r) {
            const float Lv = __shfl(Lacc[qg][r], quad << 4, 64);
            const float inv = 1.0f / Lv;
            const int token = qt * 128 + wv * 32 + qg * 16 + quad * 4 + r;
#pragma unroll
            for (int tn = 0; tn < 4; ++tn) {
                const int col = h * 64 + tn * 16 + l15;
                Zcat[(size_t)(b * 1024 + token) * 768 + col] = f2b(o_acc[qg][tn][r] * inv);
            }
        }
    }
}

// ===========================================================================
// Phase C: out = Zcat @ Dcat^T + bias. BK=64 (12 iters), reg-staged with
// chunk-XOR swizzle + next-iter prefetch under MFMAs. bid in [0, 768).
// ===========================================================================
__device__ __forceinline__ void phaseC(
    const int bid, const int t, char* smem,
    const u16* __restrict__ Zcat, const u16* __restrict__ Dcat,
    float* __restrict__ outp, const float* __restrict__ bias)
{
    u16* As = (u16*)smem;                 // 16384 B (128x64, swizzled)
    u16* Bs = (u16*)(smem + 16384);       //  8192 B (64x64, swizzled)

    const int lane = t & 63, wv = t >> 6;
    const int l15 = lane & 15, quad = lane >> 4;
    const f32x4 zero4 = {0.f, 0.f, 0.f, 0.f};

    const int lin = bid;                           // 0..767
    const int xcd = lin & 7, j = lin >> 3;         // j 0..95
    const int colT = j % 12, rowhi = j / 12;       // rowhi 0..7
    const int rowBase = (rowhi * 8 + xcd) * 128;
    const int colBase = colT * 64;

    const int srowA = wv * 32 + (lane >> 2);       // rows srowA and srowA+16
    const int srowB = wv * 16 + (lane >> 2);       // 0..63
    const int sc4   = lane & 3;
    const int scol  = sc4 * 16;                    // u16 cols 0/16/32/48
    const int swa0 = ((sc4 * 2)     ^ (srowA & 7)) * 8;
    const int swa1 = ((sc4 * 2 + 1) ^ (srowA & 7)) * 8;
    const int swb0 = ((sc4 * 2)     ^ (srowB & 7)) * 8;
    const int swb1 = ((sc4 * 2 + 1) ^ (srowB & 7)) * 8;
    const u16* aSrc = Zcat + (size_t)(rowBase + srowA) * 768 + scol;
    const u16* bSrc = Dcat + (size_t)(colBase + srowB) * 768 + scol;

    int4 ar0 = *(const int4*)(aSrc);
    int4 ar1 = *(const int4*)(aSrc + 8);
    int4 ar2 = *(const int4*)(aSrc + 16 * 768);
    int4 ar3 = *(const int4*)(aSrc + 16 * 768 + 8);
    int4 br0 = *(const int4*)(bSrc);
    int4 br1 = *(const int4*)(bSrc + 8);

    f32x4 acc[2][4];
#pragma unroll
    for (int tm = 0; tm < 2; ++tm)
#pragma unroll
        for (int tn = 0; tn < 4; ++tn) acc[tm][tn] = zero4;

    for (int kk = 0; kk < 768; kk += 64) {
        __syncthreads();
        *(int4*)&As[srowA * 64 + swa0]        = ar0;
        *(int4*)&As[srowA * 64 + swa1]        = ar1;
        *(int4*)&As[(srowA + 16) * 64 + swa0] = ar2;
        *(int4*)&As[(srowA + 16) * 64 + swa1] = ar3;
        *(int4*)&Bs[srowB * 64 + swb0]        = br0;
        *(int4*)&Bs[srowB * 64 + swb1]        = br1;
        __syncthreads();

        if (kk < 704) {
            ar0 = *(const int4*)(aSrc + kk + 64);
            ar1 = *(const int4*)(aSrc + kk + 72);
            ar2 = *(const int4*)(aSrc + 16 * 768 + kk + 64);
            ar3 = *(const int4*)(aSrc + 16 * 768 + kk + 72);
            br0 = *(const int4*)(bSrc + kk + 64);
            br1 = *(const int4*)(bSrc + kk + 72);
        }

#pragma unroll
        for (int ks = 0; ks < 2; ++ks) {
            bf16x8 af[2], bfm[4];
#pragma unroll
            for (int tm = 0; tm < 2; ++tm) {
                const int arow = wv * 32 + tm * 16 + l15;
                af[tm] = *(const bf16x8*)
                    &As[arow * 64 + ((ks * 4 + quad) ^ (arow & 7)) * 8];
            }
#pragma unroll
            for (int tn = 0; tn < 4; ++tn) {
                const int brow = tn * 16 + l15;
                bfm[tn] = *(const bf16x8*)
                    &Bs[brow * 64 + ((ks * 4 + quad) ^ (brow & 7)) * 8];
            }
#pragma unroll
            for (int tm = 0; tm < 2; ++tm)
#pragma unroll
                for (int tn = 0; tn < 4; ++tn)
                    acc[tm][tn] = __builtin_amdgcn_mfma_f32_16x16x32_bf16(
                        af[tm], bfm[tn], acc[tm][tn], 0, 0, 0);
        }
    }

#pragma unroll
    for (int tm = 0; tm < 2; ++tm) {
        const int grow = rowBase + wv * 32 + tm * 16 + quad * 4;
#pragma unroll
        for (int tn = 0; tn < 4; ++tn) {
            const int gcol = colBase + tn * 16 + l15;
            const float bv = bias[gcol];
#pragma unroll
            for (int r = 0; r < 4; ++r)
                outp[(size_t)(grow + r) * 768 + gcol] = acc[tm][tn][r] + bv;
        }
    }
}

// ===========================================================================
// Mega kernel: phase A -> fine-grained producer wait -> phase B -> gbar ->
// phase C. Fallback kernels keep the 3-launch path (waits degenerate).
// ===========================================================================
__global__ __launch_bounds__(256, 3) void mega(
    const float* __restrict__ X,
    const float* __restrict__ Wq0, const float* __restrict__ Wq1, const float* __restrict__ Wq2,
    const float* __restrict__ Wk0, const float* __restrict__ Wk1, const float* __restrict__ Wk2,
    const float* __restrict__ Wv0, const float* __restrict__ Wv1, const float* __restrict__ Wv2,
    const float* __restrict__ PW, const float* __restrict__ bias,
    u16* __restrict__ T, u16* __restrict__ tvt,
    u16* __restrict__ MqkT, u16* __restrict__ Dcat,
    u16* __restrict__ Zcat, float* __restrict__ outp)
{
    __shared__ __align__(16) char smem[36864];
    const int bid = blockIdx.x, t = threadIdx.x;

    // Launch index: g_gen[1] is stable at entry (gbar(1) can't fire until
    // every block of this launch has started).
    const unsigned G = __hip_atomic_load(&g_gen[1], __ATOMIC_ACQUIRE,
                                         __HIP_MEMORY_SCOPE_AGENT);

    phaseA(bid, t, smem, X, Wq0, Wq1, Wq2, Wk0, Wk1, Wk2, Wv0, Wv1, Wv2, PW,
           T, tvt, MqkT, Dcat);

    // Fine-grained wait (replaces gbar(0)): this block's flash work needs
    // only batch b's 48 gemm producers + the 48 MqkT producers.
    {
        const int b_need = (bid % 96) / 12;
        __syncthreads();
        if (t == 0) {
            const unsigned tgt = 48u * (G + 1u);
            unsigned spins = 0;
            while (__hip_atomic_load(&g_acnt[b_need], __ATOMIC_ACQUIRE,
                                     __HIP_MEMORY_SCOPE_AGENT) < tgt ||
                   __hip_atomic_load(&g_mcnt, __ATOMIC_ACQUIRE,
                                     __HIP_MEMORY_SCOPE_AGENT) < tgt) {
                __builtin_amdgcn_s_sleep(2);
                if (++spins > (1u << 22)) break;   // failsafe
            }
            __threadfence();
        }
        __syncthreads();
    }

    phaseB(bid, t, smem, T, MqkT, tvt, Zcat);
    gbar(1, 768u);
    phaseC(bid, t, smem, Zcat, Dcat, outp, bias);
}

__global__ __launch_bounds__(256, 2) void k_prep(
    const float* __restrict__ X,
    const float* __restrict__ Wq0, const float* __restrict__ Wq1, const float* __restrict__ Wq2,
    const float* __restrict__ Wk0, const float* __restrict__ Wk1, const float* __restrict__ Wk2,
    const float* __restrict__ Wv0, const float* __restrict__ Wv1, const float* __restrict__ Wv2,
    const float* __restrict__ PW,
    u16* __restrict__ T, u16* __restrict__ tvt,
    u16* __restrict__ MqkT, u16* __restrict__ Dcat)
{
    __shared__ __align__(16) char smem[36864];
    phaseA(blockIdx.x, threadIdx.x, smem, X, Wq0, Wq1, Wq2, Wk0, Wk1, Wk2,
           Wv0, Wv1, Wv2, PW, T, tvt, MqkT, Dcat);
}

__global__ __launch_bounds__(256, 3) void k_flash(
    const u16* __restrict__ T, const u16* __restrict__ MqkT,
    const u16* __restrict__ tvt, u16* __restrict__ Zcat)
{
    __shared__ __align__(16) char smem[36864];
    phaseB(blockIdx.x + 96 * blockIdx.y, threadIdx.x, smem, T, MqkT, tvt, Zcat);
}

__global__ __launch_bounds__(256, 3) void k_out(
    const u16* __restrict__ Zcat, const u16* __restrict__ Dcat,
    float* __restrict__ outp, const float* __restrict__ bias)
{
    __shared__ __align__(16) char smem[36864];
    phaseC(blockIdx.x, threadIdx.x, smem, Zcat, Dcat, outp, bias);
}

// ---------------------------------------------------------------------------
extern "C" void kernel_launch(void* const* d_in, const int* in_sizes, int n_in,
                              void* d_out, int out_size, void* d_ws, size_t ws_size,
                              hipStream_t stream)
{
    const float* x      = (const float*)d_in[0];
    const float* Wq0    = (const float*)d_in[1];
    const float* Wq1    = (const float*)d_in[2];
    const float* Wq2    = (const float*)d_in[3];
    const float* Wk0    = (const float*)d_in[4];
    const float* Wk1    = (const float*)d_in[5];
    const float* Wk2    = (const float*)d_in[6];
    const float* Wv0    = (const float*)d_in[7];
    const float* Wv1    = (const float*)d_in[8];
    const float* Wv2    = (const float*)d_in[9];
    const float* proj_w = (const float*)d_in[10];
    const float* proj_b = (const float*)d_in[11];
    float* outp = (float*)d_out;

    char* ws = (char*)d_ws;
    u16* T    = (u16*)ws;                       // 8192*128*2 = 2,097,152 B
    u16* tvt  = (u16*)(ws + 2097152);           // 64*8192*2  = 1,048,576 B
    u16* MqkT = (u16*)(ws + 3440640);           //    98,304 B
    u16* Dcat = (u16*)(ws + 3538944);           // 1,179,648 B
    u16* Zcat = (u16*)(ws + 4718592);           // 12,582,912 B; end = 17,301,504 B

    static int use_mega = -1;
    if (use_mega < 0) {
        int nb = 0;
        hipError_t e = hipOccupancyMaxActiveBlocksPerMultiprocessor(&nb, mega, 256, 0);
        use_mega = (e == hipSuccess && nb >= 3) ? 1 : 0;
    }

    if (use_mega) {
        mega<<<768, 256, 0, stream>>>(x, Wq0, Wq1, Wq2, Wk0, Wk1, Wk2,
                                      Wv0, Wv1, Wv2, proj_w, proj_b,
                                      T, tvt, MqkT, Dcat, Zcat, outp);
    } else {
        k_prep<<<720, 256, 0, stream>>>(x, Wq0, Wq1, Wq2, Wk0, Wk1, Wk2,
                                        Wv0, Wv1, Wv2, proj_w,
                                        T, tvt, MqkT, Dcat);
        k_flash<<<dim3(96, 8), 256, 0, stream>>>(T, MqkT, tvt, Zcat);
        k_out<<<768, 256, 0, stream>>>(Zcat, Dcat, outp, proj_b);
    }
}

// Round 11
// 153.366 us; speedup vs baseline: 1.1426x; 1.1426x over previous
//
#include <hip/hip_runtime.h>

typedef unsigned short u16;
typedef __attribute__((ext_vector_type(8))) short bf16x8;
typedef __attribute__((ext_vector_type(4))) float f32x4;
typedef __attribute__((ext_vector_type(4))) unsigned short u16x4;
typedef __attribute__((ext_vector_type(8))) unsigned short u16x8;

#define AS1 __attribute__((address_space(1)))
#define AS3 __attribute__((address_space(3)))

__device__ __forceinline__ u16 f2b(float f) {
    unsigned u = __float_as_uint(f);
    unsigned r = 0x7fffu + ((u >> 16) & 1u);
    return (u16)((u + r) >> 16);
}

// pack hi16(p1):hi16(p0) in one v_perm_b32 (truncating bf16 convert x2)
__device__ __forceinline__ unsigned packtrunc(float p0, float p1) {
#if __has_builtin(__builtin_amdgcn_perm)
    return __builtin_amdgcn_perm(__float_as_uint(p1), __float_as_uint(p0), 0x07060302u);
#else
    return (__float_as_uint(p0) >> 16) | (__float_as_uint(p1) & 0xffff0000u);
#endif
}

#if __has_builtin(__builtin_amdgcn_exp2f)
#define EXP2(x) __builtin_amdgcn_exp2f(x)
#else
#define EXP2(x) exp2f(x)
#endif

// ---------------------------------------------------------------------------
// Manual grid barrier (capture-safe). Device globals survive ws re-poison;
// gen grows monotonically across graph replays; cnt self-resets.
// ---------------------------------------------------------------------------
__device__ unsigned g_cnt[2];
__device__ unsigned g_gen[2];

__device__ __forceinline__ void gbar(int i, unsigned nblk) {
    __syncthreads();
    if (threadIdx.x == 0) {
        __threadfence();
        const unsigned my = __hip_atomic_load(&g_gen[i], __ATOMIC_RELAXED,
                                              __HIP_MEMORY_SCOPE_AGENT);
        const unsigned v = __hip_atomic_fetch_add(&g_cnt[i], 1u, __ATOMIC_ACQ_REL,
                                                  __HIP_MEMORY_SCOPE_AGENT);
        if (v == nblk - 1u) {
            __hip_atomic_store(&g_cnt[i], 0u, __ATOMIC_RELAXED,
                               __HIP_MEMORY_SCOPE_AGENT);
            __threadfence();
            __hip_atomic_fetch_add(&g_gen[i], 1u, __ATOMIC_ACQ_REL,
                                   __HIP_MEMORY_SCOPE_AGENT);
        } else {
            unsigned spins = 0;
            while (__hip_atomic_load(&g_gen[i], __ATOMIC_ACQUIRE,
                                     __HIP_MEMORY_SCOPE_AGENT) == my) {
                __builtin_amdgcn_s_sleep(2);
                if (++spins > (1u << 22)) break;   // failsafe: never hang
            }
        }
        __threadfence();
    }
    __syncthreads();
}

// ===========================================================================
// Phase A: fused gemm_t (inline-G, BK=64, chunk-XOR swizzled LDS) + MqkT +
// Dcat prep. bid in [0, 720).
// ===========================================================================
__device__ __forceinline__ void phaseA(
    const int bid, const int t, char* smem,
    const float* __restrict__ X,
    const float* __restrict__ Wq0, const float* __restrict__ Wq1, const float* __restrict__ Wq2,
    const float* __restrict__ Wk0, const float* __restrict__ Wk1, const float* __restrict__ Wk2,
    const float* __restrict__ Wv0, const float* __restrict__ Wv1, const float* __restrict__ Wv2,
    const float* __restrict__ PW,
    u16* __restrict__ T, u16* __restrict__ tvt,
    u16* __restrict__ MqkT, u16* __restrict__ Dcat)
{
    const f32x4 zero4 = {0.f, 0.f, 0.f, 0.f};
    if (bid < 384) {
        // ---- gemm_t, BK=64: 12 iters (24 barriers). LDS end = 36,096 B.
        // As/Bs [64][64] u16, 16B-chunk XOR swizzle: phys_chunk = c ^ (row&7)
        // -> conflict-free b128 writes AND reads (uniform 8 slots/bank).
        u16*   As  = (u16*)smem;                 //  8192 B
        u16*   Bs  = (u16*)(smem + 8192);        //  8192 B
        float* W1t = (float*)(smem + 16384);     //  3072 B  [h*64+r]
        float* W2t = (float*)(smem + 19456);     // 16640 B  [r*65+d]

        const int lane = t & 63, wv = t >> 6;
        const int l15 = lane & 15, quad = lane >> 4;

        const int lin = bid;                     // 0..383
        const int xcd = lin & 7, j = lin >> 3;   // j 0..47
        const int col = j % 3, rowhi = j / 3;    // rowhi 0..15
        const int rowBase = (rowhi * 8 + xcd) * 64;
        const int colBase = col * 64;

        const float* W1g = (col == 0) ? Wq1 : (col == 1) ? Wk1 : Wv1;
        const float* W2g = (col == 0) ? Wq2 : (col == 1) ? Wk2 : Wv2;
        for (int i = t; i < 768; i += 256) W1t[i] = W1g[i];
        for (int i = t; i < 4096; i += 256) {
            const int d = i >> 6, r = i & 63;
            W2t[r * 65 + d] = W2g[i];            // transpose: [r][d]
        }

        const int srow = t >> 2;            // 0..63
        const int sc4  = t & 3;             // chunk pair base = sc4*2
        const int scol = sc4 * 16;          // 0/16/32/48 (u16 cols)
        const int swa = ((sc4 * 2)     ^ (srow & 7)) * 8;
        const int swb = ((sc4 * 2 + 1) ^ (srow & 7)) * 8;
        const float* aS = X + (size_t)(rowBase + srow) * 768 + scol;

        float4 a0 = *(const float4*)(aS);
        float4 a1 = *(const float4*)(aS + 4);
        float4 a2 = *(const float4*)(aS + 8);
        float4 a3 = *(const float4*)(aS + 12);

        f32x4 acc[4];
#pragma unroll
        for (int tn = 0; tn < 4; ++tn) acc[tn] = zero4;

        for (int kk = 0; kk < 768; kk += 64) {
            __syncthreads();
            u16x8 ap0, ap1;
            ap0[0] = f2b(a0.x); ap0[1] = f2b(a0.y); ap0[2] = f2b(a0.z); ap0[3] = f2b(a0.w);
            ap0[4] = f2b(a1.x); ap0[5] = f2b(a1.y); ap0[6] = f2b(a1.z); ap0[7] = f2b(a1.w);
            ap1[0] = f2b(a2.x); ap1[1] = f2b(a2.y); ap1[2] = f2b(a2.z); ap1[3] = f2b(a2.w);
            ap1[4] = f2b(a3.x); ap1[5] = f2b(a3.y); ap1[6] = f2b(a3.z); ap1[7] = f2b(a3.w);
            *(u16x8*)&As[srow * 64 + swa] = ap0;
            *(u16x8*)&As[srow * 64 + swb] = ap1;
            // B-tile: G[colBase+srow][kk+scol .. +15] = W1[h,r]*W2[d,r]
            {
                const int c0 = kk + scol;
                const int hh = c0 >> 6, dd = c0 & 63;   // 16 consec d, same h
                const float w1v = W1t[hh * 64 + srow];
                u16x8 bp0, bp1;
#pragma unroll
                for (int jj = 0; jj < 8; ++jj)
                    bp0[jj] = f2b(w1v * W2t[srow * 65 + dd + jj]);
#pragma unroll
                for (int jj = 0; jj < 8; ++jj)
                    bp1[jj] = f2b(w1v * W2t[srow * 65 + dd + 8 + jj]);
                *(u16x8*)&Bs[srow * 64 + swa] = bp0;
                *(u16x8*)&Bs[srow * 64 + swb] = bp1;
            }
            __syncthreads();

            if (kk < 704) {
                a0 = *(const float4*)(aS + kk + 64);
                a1 = *(const float4*)(aS + kk + 68);
                a2 = *(const float4*)(aS + kk + 72);
                a3 = *(const float4*)(aS + kk + 76);
            }

            const int arow = wv * 16 + l15;
#pragma unroll
            for (int ks = 0; ks < 2; ++ks) {
                const bf16x8 af = *(const bf16x8*)
                    &As[arow * 64 + ((ks * 4 + quad) ^ (arow & 7)) * 8];
#pragma unroll
                for (int tn = 0; tn < 4; ++tn) {
                    const int brow = tn * 16 + l15;
                    const bf16x8 bf = *(const bf16x8*)
                        &Bs[brow * 64 + ((ks * 4 + quad) ^ (brow & 7)) * 8];
                    acc[tn] = __builtin_amdgcn_mfma_f32_16x16x32_bf16(af, bf, acc[tn], 0, 0, 0);
                }
            }
        }

        if (colBase < 128) {
#pragma unroll
            for (int tn = 0; tn < 4; ++tn) {
                const int c = colBase + tn * 16 + l15;
#pragma unroll
                for (int r = 0; r < 4; ++r) {
                    const int grow = rowBase + wv * 16 + quad * 4 + r;
                    T[(size_t)grow * 128 + c] = f2b(acc[tn][r]);
                }
            }
        } else {
#pragma unroll
            for (int tn = 0; tn < 4; ++tn) {
                const int rr = tn * 16 + l15;                    // r index 0..63
                const int grow = rowBase + wv * 16 + quad * 4;   // token base
                u16x4 pk;
                pk.x = f2b(acc[tn][0]); pk.y = f2b(acc[tn][1]);
                pk.z = f2b(acc[tn][2]); pk.w = f2b(acc[tn][3]);
                *(u16x4*)(tvt + (size_t)rr * 8192 + grow) = pk;
            }
        }
    } else if (bid < 432) {
        // ---- MqkT section (48 blocks) ----
        float* wq = (float*)smem;                // 16640 B
        float* wk = (float*)(smem + 16640);      // 16640 B
        const int hq = bid - 384;                // 0..47
        const int h = hq >> 2, quarter = hq & 3;
        const float qs = 0.125f * 1.4426950408889634f;
        for (int i = t; i < 4096; i += 256) {
            const int dd = i >> 6, r = i & 63;
            wq[dd * 65 + r] = Wq0[(h * 64 + dd) * 64 + r] * qs;
            wk[dd * 65 + r] = Wk0[(h * 64 + dd) * 64 + r];
        }
        __syncthreads();
        const int j0 = quarter * 1024 + t * 4;
        const int r2 = j0 >> 6, r1b = j0 & 63;   // output row = r2, packed cols = r1
        u16x4 pk;
#pragma unroll
        for (int jj = 0; jj < 4; ++jj) {
            float acc = 0.f;
#pragma unroll
            for (int dd = 0; dd < 64; ++dd)
                acc += wk[dd * 65 + r2] * wq[dd * 65 + r1b + jj];
            ((u16*)&pk)[jj] = f2b(acc);
        }
        *(u16x4*)(MqkT + (size_t)(h * 64 + r2) * 64 + r1b) = pk;
    } else if (bid < 720) {
        // ---- Dcat section (288 blocks) ----
        float* w0s = (float*)smem;               // 16640 B  [d][r]
        float* pws = (float*)(smem + 16640);     //  8320 B  [mi][d]
        const int hb = bid - 432;                // 0..287
        const int h = hb / 24, mBase = (hb - h * 24) * 32;
        for (int i = t; i < 4096; i += 256) {
            const int d = i >> 6, r = i & 63;
            w0s[d * 65 + r] = Wv0[(h * 64 + d) * 64 + r];
        }
        for (int i = t; i < 2048; i += 256) {
            const int mi = i >> 6, d = i & 63;
            pws[mi * 65 + d] = PW[(size_t)(mBase + mi) * 768 + h * 64 + d];
        }
        __syncthreads();
        const int r = t & 63, mi0 = t >> 6;
        float w0c[64];
#pragma unroll
        for (int d = 0; d < 64; ++d) w0c[d] = w0s[d * 65 + r];
        for (int mi = mi0; mi < 32; mi += 4) {
            float acc = 0.f;
#pragma unroll
            for (int d = 0; d < 64; ++d) acc += pws[mi * 65 + d] * w0c[d];
            Dcat[(size_t)(mBase + mi) * 768 + h * 64 + r] = f2b(acc);
        }
    }
}

// ===========================================================================
// Phase B: flash attention v10 body (unchanged). bid in [0, 768).
// ===========================================================================
__device__ __forceinline__ void phaseB(
    const int bid, const int t, char* smem,
    const u16* __restrict__ T, const u16* __restrict__ MqkT,
    const u16* __restrict__ tvt, u16* __restrict__ Zcat)
{
    const int bh = bid % 96;
    const int qt = bid / 96;            // 0..7 (128 q rows each)
    const int b = bh / 12, h = bh - b * 12;
    const u16* qp = T + ((size_t)b * 1024 + qt * 128) * 128;   // t_q rows
    const u16* kp = T + (size_t)b * 1024 * 128 + 64;           // t_k rows
    const u16* vp = tvt + b * 1024;     // tvt[r][8192]

    u16* const B0raw = (u16*)smem;             // [0, 18432) B
    u16* const B1raw = (u16*)(smem + 18432);   // [18432, 36864) B

    const int lane = t & 63, wv = t >> 6;
    const int l15 = lane & 15, quad = lane >> 4;
    const f32x4 zero4 = {0.f, 0.f, 0.f, 0.f};

    // t_q A-fragments (rows = q, cols = r1)
    bf16x8 qf[2][2];
#pragma unroll
    for (int qg = 0; qg < 2; ++qg) {
        const u16* qrow = qp + (size_t)(wv * 32 + qg * 16 + l15) * 128;
        qf[qg][0] = *(const bf16x8*)(qrow + quad * 8);
        qf[qg][1] = *(const bf16x8*)(qrow + 32 + quad * 8);
    }

    const int srow = t >> 2;            // key-row / r-row 0..63
    const int scol = (t & 3) * 16;
    const int p5 = srow & 31;
    const int lrow = (srow & 32) | ((p5 & 4) << 2) | ((p5 & 16) >> 1)
                   | ((p5 & 8) >> 1) | (p5 & 3);   // permuted K row

    bf16x8 vone = {};
    if (l15 == 0) {
#pragma unroll
        for (int j = 0; j < 8; ++j) vone[j] = (short)0x3F80;
    }

    // prefetch tile 0 (t_k + v) — overlaps the Wq prologue
    int4 kr0 = *(const int4*)(kp + (size_t)srow * 128 + scol);
    int4 kr1 = *(const int4*)(kp + (size_t)srow * 128 + scol + 8);
    int4 vr0 = *(const int4*)(vp + (size_t)srow * 8192 + scol);
    int4 vr1 = *(const int4*)(vp + (size_t)srow * 8192 + scol + 8);

    // ---- Wq = t_q x Mqk_h prologue ----
    {
        f32x4 Wt[2][4];
#pragma unroll
        for (int qg = 0; qg < 2; ++qg)
#pragma unroll
            for (int tn = 0; tn < 4; ++tn) Wt[qg][tn] = zero4;
#pragma unroll
        for (int ks = 0; ks < 2; ++ks) {
#pragma unroll
            for (int tn = 0; tn < 4; ++tn) {
                const bf16x8 mb = *(const bf16x8*)(
                    MqkT + (size_t)(h * 64 + tn * 16 + l15) * 64 + ks * 32 + quad * 8);
                Wt[0][tn] = __builtin_amdgcn_mfma_f32_16x16x32_bf16(qf[0][ks], mb, Wt[0][tn], 0, 0, 0);
                Wt[1][tn] = __builtin_amdgcn_mfma_f32_16x16x32_bf16(qf[1][ks], mb, Wt[1][tn], 0, 0, 0);
            }
        }
        // C-layout -> LDS Ws (rows = q_local, cols = r2), Ws = B1raw overlay
#pragma unroll
        for (int qg = 0; qg < 2; ++qg)
#pragma unroll
            for (int tn = 0; tn < 4; ++tn)
#pragma unroll
                for (int r = 0; r < 4; ++r)
                    B1raw[(wv * 32 + qg * 16 + quad * 4 + r) * 72 + tn * 16 + l15] =
                        f2b(Wt[qg][tn][r]);
    }
    __syncthreads();
    // B-fragments of Wq: B[n=q][k=r2]
    bf16x8 wf[2][2];
#pragma unroll
    for (int qg = 0; qg < 2; ++qg) {
        wf[qg][0] = *(const bf16x8*)&B1raw[(wv * 32 + qg * 16 + l15) * 72 + quad * 8];
        wf[qg][1] = *(const bf16x8*)&B1raw[(wv * 32 + qg * 16 + l15) * 72 + 32 + quad * 8];
    }

    // stage tile 0 -> buf0 while everyone still holds wf in regs
    *(int4*)&B0raw[lrow * 72 + scol]                 = kr0;
    *(int4*)&B0raw[lrow * 72 + scol + 8]             = kr1;
    *(int4*)&B0raw[64 * 72 + srow * 72 + scol]       = vr0;
    *(int4*)&B0raw[64 * 72 + srow * 72 + scol + 8]   = vr1;
    // prefetch tile 1 into regs
    kr0 = *(const int4*)(kp + (size_t)(64 + srow) * 128 + scol);
    kr1 = *(const int4*)(kp + (size_t)(64 + srow) * 128 + scol + 8);
    vr0 = *(const int4*)(vp + (size_t)srow * 8192 + 64 + scol);
    vr1 = *(const int4*)(vp + (size_t)srow * 8192 + 64 + scol + 8);
    __syncthreads();   // buf0 visible; all waves past wf-read

    f32x4 o_acc[2][4];
    f32x4 Lacc[2] = {zero4, zero4};
#pragma unroll
    for (int qg = 0; qg < 2; ++qg)
#pragma unroll
        for (int tn = 0; tn < 4; ++tn) o_acc[qg][tn] = zero4;

#define STAGE(NB)                                                               \
    {                                                                           \
        *(int4*)&NB[lrow * 72 + scol]               = kr0;                      \
        *(int4*)&NB[lrow * 72 + scol + 8]           = kr1;                      \
        *(int4*)&NB[64 * 72 + srow * 72 + scol]     = vr0;                      \
        *(int4*)&NB[64 * 72 + srow * 72 + scol + 8] = vr1;                      \
    }
#define PREFETCH(KT)                                                            \
    {                                                                           \
        kr0 = *(const int4*)(kp + (size_t)((KT) * 64 + srow) * 128 + scol);     \
        kr1 = *(const int4*)(kp + (size_t)((KT) * 64 + srow) * 128 + scol + 8); \
        vr0 = *(const int4*)(vp + (size_t)srow * 8192 + (KT) * 64 + scol);      \
        vr1 = *(const int4*)(vp + (size_t)srow * 8192 + (KT) * 64 + scol + 8);  \
    }
#define FLASH_TILE(KB)                                                          \
    {                                                                           \
        f32x4 Sacc[2][4];                                                       \
        _Pragma("unroll")                                                       \
        for (int qg = 0; qg < 2; ++qg)                                          \
            _Pragma("unroll")                                                   \
            for (int tk = 0; tk < 4; ++tk) Sacc[qg][tk] = zero4;                \
        _Pragma("unroll")                                                       \
        for (int ks = 0; ks < 2; ++ks) {                                        \
            _Pragma("unroll")                                                   \
            for (int tk = 0; tk < 4; ++tk) {                                    \
                const bf16x8 kf = *(const bf16x8*)&KB[(tk * 16 + l15) * 72 + ks * 32 + quad * 8]; \
                Sacc[0][tk] = __builtin_amdgcn_mfma_f32_16x16x32_bf16(kf, wf[0][ks], Sacc[0][tk], 0, 0, 0); \
                Sacc[1][tk] = __builtin_amdgcn_mfma_f32_16x16x32_bf16(kf, wf[1][ks], Sacc[1][tk], 0, 0, 0); \
            }                                                                   \
        }                                                                       \
        union { bf16x8 v; unsigned u[4]; } pf[2][2];                            \
        _Pragma("unroll")                                                       \
        for (int qg = 0; qg < 2; ++qg)                                          \
            _Pragma("unroll")                                                   \
            for (int tk = 0; tk < 4; ++tk) {                                    \
                const float p0 = EXP2(Sacc[qg][tk][0]);                         \
                const float p1 = EXP2(Sacc[qg][tk][1]);                         \
                const float p2 = EXP2(Sacc[qg][tk][2]);                         \
                const float p3 = EXP2(Sacc[qg][tk][3]);                         \
                const int g = tk >> 1, hf = (tk & 1) * 2;                       \
                pf[qg][g].u[hf + 0] = packtrunc(p0, p1);                        \
                pf[qg][g].u[hf + 1] = packtrunc(p2, p3);                        \
            }                                                                   \
        _Pragma("unroll")                                                       \
        for (int g = 0; g < 2; ++g) {                                           \
            _Pragma("unroll")                                                   \
            for (int tn = 0; tn < 4; ++tn) {                                    \
                const bf16x8 vf = *(const bf16x8*)&KB[64 * 72 + (tn * 16 + l15) * 72 + g * 32 + quad * 8]; \
                o_acc[0][tn] = __builtin_amdgcn_mfma_f32_16x16x32_bf16(pf[0][g].v, vf, o_acc[0][tn], 0, 0, 0); \
                o_acc[1][tn] = __builtin_amdgcn_mfma_f32_16x16x32_bf16(pf[1][g].v, vf, o_acc[1][tn], 0, 0, 0); \
            }                                                                   \
            Lacc[0] = __builtin_amdgcn_mfma_f32_16x16x32_bf16(pf[0][g].v, vone, Lacc[0], 0, 0, 0); \
            Lacc[1] = __builtin_amdgcn_mfma_f32_16x16x32_bf16(pf[1][g].v, vone, Lacc[1], 0, 0, 0); \
        }                                                                       \
    }

    for (int t8 = 0; t8 < 8; ++t8) {
        const int kt0 = 2 * t8;
        STAGE(B1raw);
        if (t8 < 7) PREFETCH(kt0 + 2);
        FLASH_TILE(B0raw);
        __syncthreads();
        if (t8 < 7) {
            STAGE(B0raw);
            PREFETCH(kt0 + 3);
        }
        FLASH_TILE(B1raw);
        if (t8 < 7) __syncthreads();
    }

#undef STAGE
#undef PREFETCH
#undef FLASH_TILE

    // epilogue: Z[token][h*64 + r'], r' = tn*16+l15
#pragma unroll
    for (int qg = 0; qg < 2; ++qg) {
#pragma unroll
        for (int r = 0; r < 4; ++r) {
            const float Lv = __shfl(Lacc[qg][r], quad << 4, 64);
            const float inv = 1.0f / Lv;
            const int token = qt * 128 + wv * 32 + qg * 16 + quad * 4 + r;
#pragma unroll
            for (int tn = 0; tn < 4; ++tn) {
                const int col = h * 64 + tn * 16 + l15;
                Zcat[(size_t)(b * 1024 + token) * 768 + col] = f2b(o_acc[qg][tn][r] * inv);
            }
        }
    }
}

// ===========================================================================
// Phase C: out = Zcat @ Dcat^T + bias. BK=64 (12 iters), reg-staged with
// chunk-XOR swizzle + next-iter prefetch under MFMAs. Stages BOTH rows of
// the (srowA, srowA+16) pair — 4 A-int4s per thread. bid in [0, 768).
// ===========================================================================
__device__ __forceinline__ void phaseC(
    const int bid, const int t, char* smem,
    const u16* __restrict__ Zcat, const u16* __restrict__ Dcat,
    float* __restrict__ outp, const float* __restrict__ bias)
{
    u16* As = (u16*)smem;                 // 16384 B (128x64, swizzled)
    u16* Bs = (u16*)(smem + 16384);       //  8192 B (64x64, swizzled)

    const int lane = t & 63, wv = t >> 6;
    const int l15 = lane & 15, quad = lane >> 4;
    const f32x4 zero4 = {0.f, 0.f, 0.f, 0.f};

    const int lin = bid;                           // 0..767
    const int xcd = lin & 7, j = lin >> 3;         // j 0..95
    const int colT = j % 12, rowhi = j / 12;       // rowhi 0..7
    const int rowBase = (rowhi * 8 + xcd) * 128;
    const int colBase = colT * 64;

    const int srowA = wv * 32 + (lane >> 2);       // rows srowA and srowA+16
    const int srowB = wv * 16 + (lane >> 2);       // 0..63
    const int sc4   = lane & 3;
    const int scol  = sc4 * 16;                    // u16 cols 0/16/32/48
    const int swa0 = ((sc4 * 2)     ^ (srowA & 7)) * 8;
    const int swa1 = ((sc4 * 2 + 1) ^ (srowA & 7)) * 8;
    const int swb0 = ((sc4 * 2)     ^ (srowB & 7)) * 8;
    const int swb1 = ((sc4 * 2 + 1) ^ (srowB & 7)) * 8;
    const u16* aSrc = Zcat + (size_t)(rowBase + srowA) * 768 + scol;
    const u16* bSrc = Dcat + (size_t)(colBase + srowB) * 768 + scol;

    int4 ar0 = *(const int4*)(aSrc);
    int4 ar1 = *(const int4*)(aSrc + 8);
    int4 ar2 = *(const int4*)(aSrc + 16 * 768);
    int4 ar3 = *(const int4*)(aSrc + 16 * 768 + 8);
    int4 br0 = *(const int4*)(bSrc);
    int4 br1 = *(const int4*)(bSrc + 8);

    f32x4 acc[2][4];
#pragma unroll
    for (int tm = 0; tm < 2; ++tm)
#pragma unroll
        for (int tn = 0; tn < 4; ++tn) acc[tm][tn] = zero4;

    for (int kk = 0; kk < 768; kk += 64) {
        __syncthreads();
        *(int4*)&As[srowA * 64 + swa0]        = ar0;
        *(int4*)&As[srowA * 64 + swa1]        = ar1;
        *(int4*)&As[(srowA + 16) * 64 + swa0] = ar2;
        *(int4*)&As[(srowA + 16) * 64 + swa1] = ar3;
        *(int4*)&Bs[srowB * 64 + swb0]        = br0;
        *(int4*)&Bs[srowB * 64 + swb1]        = br1;
        __syncthreads();

        if (kk < 704) {
            ar0 = *(const int4*)(aSrc + kk + 64);
            ar1 = *(const int4*)(aSrc + kk + 72);
            ar2 = *(const int4*)(aSrc + 16 * 768 + kk + 64);
            ar3 = *(const int4*)(aSrc + 16 * 768 + kk + 72);
            br0 = *(const int4*)(bSrc + kk + 64);
            br1 = *(const int4*)(bSrc + kk + 72);
        }

#pragma unroll
        for (int ks = 0; ks < 2; ++ks) {
            bf16x8 af[2], bfm[4];
#pragma unroll
            for (int tm = 0; tm < 2; ++tm) {
                const int arow = wv * 32 + tm * 16 + l15;
                af[tm] = *(const bf16x8*)
                    &As[arow * 64 + ((ks * 4 + quad) ^ (arow & 7)) * 8];
            }
#pragma unroll
            for (int tn = 0; tn < 4; ++tn) {
                const int brow = tn * 16 + l15;
                bfm[tn] = *(const bf16x8*)
                    &Bs[brow * 64 + ((ks * 4 + quad) ^ (brow & 7)) * 8];
            }
#pragma unroll
            for (int tm = 0; tm < 2; ++tm)
#pragma unroll
                for (int tn = 0; tn < 4; ++tn)
                    acc[tm][tn] = __builtin_amdgcn_mfma_f32_16x16x32_bf16(
                        af[tm], bfm[tn], acc[tm][tn], 0, 0, 0);
        }
    }

#pragma unroll
    for (int tm = 0; tm < 2; ++tm) {
        const int grow = rowBase + wv * 32 + tm * 16 + quad * 4;
#pragma unroll
        for (int tn = 0; tn < 4; ++tn) {
            const int gcol = colBase + tn * 16 + l15;
            const float bv = bias[gcol];
#pragma unroll
            for (int r = 0; r < 4; ++r)
                outp[(size_t)(grow + r) * 768 + gcol] = acc[tm][tn][r] + bv;
        }
    }
}

// ===========================================================================
// Mega kernel (normal launch + manual grid barriers) and fallback kernels.
// ===========================================================================
__global__ __launch_bounds__(256, 3) void mega(
    const float* __restrict__ X,
    const float* __restrict__ Wq0, const float* __restrict__ Wq1, const float* __restrict__ Wq2,
    const float* __restrict__ Wk0, const float* __restrict__ Wk1, const float* __restrict__ Wk2,
    const float* __restrict__ Wv0, const float* __restrict__ Wv1, const float* __restrict__ Wv2,
    const float* __restrict__ PW, const float* __restrict__ bias,
    u16* __restrict__ T, u16* __restrict__ tvt,
    u16* __restrict__ MqkT, u16* __restrict__ Dcat,
    u16* __restrict__ Zcat, float* __restrict__ outp)
{
    __shared__ __align__(16) char smem[36864];
    const int bid = blockIdx.x, t = threadIdx.x;
    if (bid < 720)
        phaseA(bid, t, smem, X, Wq0, Wq1, Wq2, Wk0, Wk1, Wk2, Wv0, Wv1, Wv2, PW,
               T, tvt, MqkT, Dcat);
    gbar(0, 768u);
    phaseB(bid, t, smem, T, MqkT, tvt, Zcat);
    gbar(1, 768u);
    phaseC(bid, t, smem, Zcat, Dcat, outp, bias);
}

__global__ __launch_bounds__(256, 2) void k_prep(
    const float* __restrict__ X,
    const float* __restrict__ Wq0, const float* __restrict__ Wq1, const float* __restrict__ Wq2,
    const float* __restrict__ Wk0, const float* __restrict__ Wk1, const float* __restrict__ Wk2,
    const float* __restrict__ Wv0, const float* __restrict__ Wv1, const float* __restrict__ Wv2,
    const float* __restrict__ PW,
    u16* __restrict__ T, u16* __restrict__ tvt,
    u16* __restrict__ MqkT, u16* __restrict__ Dcat)
{
    __shared__ __align__(16) char smem[36864];
    phaseA(blockIdx.x, threadIdx.x, smem, X, Wq0, Wq1, Wq2, Wk0, Wk1, Wk2,
           Wv0, Wv1, Wv2, PW, T, tvt, MqkT, Dcat);
}

__global__ __launch_bounds__(256, 3) void k_flash(
    const u16* __restrict__ T, const u16* __restrict__ MqkT,
    const u16* __restrict__ tvt, u16* __restrict__ Zcat)
{
    __shared__ __align__(16) char smem[36864];
    phaseB(blockIdx.x + 96 * blockIdx.y, threadIdx.x, smem, T, MqkT, tvt, Zcat);
}

__global__ __launch_bounds__(256, 3) void k_out(
    const u16* __restrict__ Zcat, const u16* __restrict__ Dcat,
    float* __restrict__ outp, const float* __restrict__ bias)
{
    __shared__ __align__(16) char smem[36864];
    phaseC(blockIdx.x, threadIdx.x, smem, Zcat, Dcat, outp, bias);
}

// ---------------------------------------------------------------------------
extern "C" void kernel_launch(void* const* d_in, const int* in_sizes, int n_in,
                              void* d_out, int out_size, void* d_ws, size_t ws_size,
                              hipStream_t stream)
{
    const float* x      = (const float*)d_in[0];
    const float* Wq0    = (const float*)d_in[1];
    const float* Wq1    = (const float*)d_in[2];
    const float* Wq2    = (const float*)d_in[3];
    const float* Wk0    = (const float*)d_in[4];
    const float* Wk1    = (const float*)d_in[5];
    const float* Wk2    = (const float*)d_in[6];
    const float* Wv0    = (const float*)d_in[7];
    const float* Wv1    = (const float*)d_in[8];
    const float* Wv2    = (const float*)d_in[9];
    const float* proj_w = (const float*)d_in[10];
    const float* proj_b = (const float*)d_in[11];
    float* outp = (float*)d_out;

    char* ws = (char*)d_ws;
    u16* T    = (u16*)ws;                       // 8192*128*2 = 2,097,152 B
    u16* tvt  = (u16*)(ws + 2097152);           // 64*8192*2  = 1,048,576 B
    u16* MqkT = (u16*)(ws + 3440640);           //    98,304 B
    u16* Dcat = (u16*)(ws + 3538944);           // 1,179,648 B
    u16* Zcat = (u16*)(ws + 4718592);           // 12,582,912 B; end = 17,301,504 B

    static int use_mega = -1;
    if (use_mega < 0) {
        int nb = 0;
        hipError_t e = hipOccupancyMaxActiveBlocksPerMultiprocessor(&nb, mega, 256, 0);
        use_mega = (e == hipSuccess && nb >= 3) ? 1 : 0;
    }

    if (use_mega) {
        mega<<<768, 256, 0, stream>>>(x, Wq0, Wq1, Wq2, Wk0, Wk1, Wk2,
                                      Wv0, Wv1, Wv2, proj_w, proj_b,
                                      T, tvt, MqkT, Dcat, Zcat, outp);
    } else {
        k_prep<<<720, 256, 0, stream>>>(x, Wq0, Wq1, Wq2, Wk0, Wk1, Wk2,
                                        Wv0, Wv1, Wv2, proj_w,
                                        T, tvt, MqkT, Dcat);
        k_flash<<<dim3(96, 8), 256, 0, stream>>>(T, MqkT, tvt, Zcat);
        k_out<<<768, 256, 0, stream>>>(Zcat, Dcat, outp, proj_b);
    }
}